// Round 5
// baseline (1740.681 us; speedup 1.0000x reference)
//
#include <hip/hip_runtime.h>
#include <hip/hip_bf16.h>

typedef __hip_bfloat16 bf16;

static constexpr int cB = 200, cN = 384, cM = 512, cH = 128;
static constexpr int cNN  = cB * cN;     // 76800
static constexpr int cE   = 2 * cB * cM; // 204800 edges
static constexpr int cTWOM = 2 * cM;     // 1024
static constexpr int ZROW = 2 * cM + cN; // 1408
static constexpr int CROW = cM + 2 * cN; // 1280
static constexpr int ZBASE = cB * ZROW;  // 281600

__device__ __forceinline__ float b2f(bf16 x) { return __bfloat162float(x); }
__device__ __forceinline__ bf16  f2b(float x) { return __float2bfloat16(x); }

// ---------------- normalize edge_index / numSwitches (int32 or int64 low words) ----
__global__ __launch_bounds__(256) void k_norm_idx(const int* __restrict__ ei_raw,
                                                  const int* __restrict__ nsw_raw,
                                                  int* __restrict__ ei, int* __restrict__ nsw) {
  int z = 0;
#pragma unroll
  for (int j = 1; j < 64; j += 2) z |= ei_raw[j];
  const int f = (z == 0) ? 1 : 0;
  const int i = blockIdx.x * 256 + threadIdx.x;
  if (i < 2 * cE) ei[i] = ei_raw[i << f];
  if (blockIdx.x == 0 && threadIdx.x < cB) nsw[threadIdx.x] = nsw_raw[threadIdx.x << f];
}

// ---------------- fills ----------------
__global__ __launch_bounds__(256) void k_fill(float* p, float v, int count) {
  int i = blockIdx.x * 256 + threadIdx.x;
  if (i < count) p[i] = v;
}

__global__ __launch_bounds__(256) void k_deg(const int* __restrict__ ei, float* deg) {
  int e = blockIdx.x * 256 + threadIdx.x;
  if (e < cE) atomicAdd(&deg[ei[cE + e]], 1.0f);
}

__global__ __launch_bounds__(256) void k_dinv(float* deg) {
  int i = blockIdx.x * 256 + threadIdx.x;
  if (i < cNN) deg[i] = rsqrtf(deg[i]);
}

// ---------------- layer 1 linear: hraw = x@W1 + b1 ----------------
__global__ __launch_bounds__(256) void k_lin1(const float* __restrict__ x, const float* __restrict__ W1,
                                              const float* __restrict__ b1, bf16* __restrict__ hraw) {
  int idx = blockIdx.x * 256 + threadIdx.x;
  if (idx >= cNN * cH) return;
  int n = idx >> 7, h = idx & 127;
  hraw[idx] = f2b(x[2 * n] * W1[h] + x[2 * n + 1] * W1[cH + h] + b1[h]);
}

// ---------------- edge scatter: agg[d] += h[s] * dinv[s] * dinv[d] ----------------
__global__ __launch_bounds__(256) void k_scat(const int* __restrict__ ei, const bf16* __restrict__ hsrc,
                                              const float* __restrict__ dinv, float* __restrict__ agg) {
  int idx = blockIdx.x * 256 + threadIdx.x;
  int e = idx >> 7, h = idx & 127;
  if (e >= cE) return;
  int s = ei[e], d = ei[cE + e];
  atomicAdd(&agg[(size_t)d * cH + h], b2f(hsrc[(size_t)s * cH + h]) * dinv[s] * dinv[d]);
}

// ---------------- relu(agg + self): out = relu(agg[i] + h[i]*dinv[n]^2) ----------------
__global__ __launch_bounds__(256) void k_reluagg(const float* __restrict__ agg, const bf16* __restrict__ hself,
                                                 const float* __restrict__ dinv, bf16* __restrict__ outh) {
  int idx = blockIdx.x * 256 + threadIdx.x;
  if (idx >= cNN * cH) return;
  int n = idx >> 7;
  float dn = dinv[n];
  float v = agg[idx] + b2f(hself[idx]) * dn * dn;
  outh[idx] = f2b(fmaxf(v, 0.0f));
}

// ---------------- layer 2 linear: h2raw = h1@W2 + b2 (no relu, no norm) ----------------
__global__ __launch_bounds__(256) void k_lin2(const bf16* __restrict__ h1, const float* __restrict__ W2,
                                              const float* __restrict__ b2v, bf16* __restrict__ h2raw) {
  __shared__ float w2s[64 * cH];   // 32 KB half-tile of W2
  __shared__ float ts[8][cH];      // 4 KB
  const int tid = threadIdx.x;
  const int n0 = blockIdx.x * 8;
  for (int i = tid; i < 8 * cH; i += 256)
    ts[i >> 7][i & 127] = b2f(h1[(size_t)(n0 + (i >> 7)) * cH + (i & 127)]);
  const int hp = (tid & 63) * 2;
  const int ng = tid >> 6;
  const int e0 = ng, e1 = ng + 4;
  float a00 = 0, a01 = 0, a10 = 0, a11 = 0;
  for (int half = 0; half < 2; ++half) {
    __syncthreads();
    for (int i = tid; i < 64 * cH; i += 256) w2s[i] = W2[half * 64 * cH + i];
    __syncthreads();
    const int kb = half * 64;
#pragma unroll 8
    for (int k = 0; k < 64; ++k) {
      const float w0 = w2s[k * cH + hp];
      const float w1 = w2s[k * cH + hp + 1];
      const float t0 = ts[e0][kb + k];
      const float t1 = ts[e1][kb + k];
      a00 = fmaf(t0, w0, a00); a01 = fmaf(t0, w1, a01);
      a10 = fmaf(t1, w0, a10); a11 = fmaf(t1, w1, a11);
    }
  }
  h2raw[(size_t)(n0 + e0) * cH + hp]     = f2b(a00 + b2v[hp]);
  h2raw[(size_t)(n0 + e0) * cH + hp + 1] = f2b(a01 + b2v[hp + 1]);
  h2raw[(size_t)(n0 + e1) * cH + hp]     = f2b(a10 + b2v[hp]);
  h2raw[(size_t)(n0 + e1) * cH + hp + 1] = f2b(a11 + b2v[hp + 1]);
}

// ---------------- x_g = sum_n xg ----------------
__global__ __launch_bounds__(128) void k_xgsum(const bf16* __restrict__ xg, float* __restrict__ x_g) {
  int b = blockIdx.x, h = threadIdx.x;
  float s = 0.f;
  const bf16* p = xg + (size_t)b * cN * cH + h;
  for (int n = 0; n < cN; ++n) s += b2f(p[(size_t)n * cH]);
  x_g[b * cH + h] = s;
}

// ---------------- per-edge MLPs, literal: feat = [xp | xc | x_g] (384 rows) ----------------
__global__ __launch_bounds__(256) void k_mlp(
    const int* __restrict__ ei, const int* __restrict__ nsw, const bf16* __restrict__ xg,
    const float* __restrict__ x_g,
    const float* __restrict__ Ws1, const float* __restrict__ bs1,
    const float* __restrict__ Ws2, const float* __restrict__ bs2,
    const float* __restrict__ Wc1, const float* __restrict__ bc1,
    const float* __restrict__ Wc2, const float* __restrict__ bc2,
    float* __restrict__ gt_w, float* __restrict__ wvp_w, float* __restrict__ wvc_w,
    float* __restrict__ pfc_w, float* __restrict__ out) {
  __shared__ float feat[384][8];   // [k][e] 12 KB
  __shared__ float hid[8][512];    // 16 KB
  __shared__ float outs_s[8][4];
  __shared__ float outs_c[8][3];
  const int tid = threadIdx.x;
  const int blk = blockIdx.x;
  const int b = blk >> 6;            // 64 blocks per batch
  const int m0 = (blk & 63) << 3;    // 8 edges per block

  {
    int e = tid >> 5, j = tid & 31;
    int m = m0 + e;
    int pn = ei[b * cTWOM + m];
    int cn = ei[b * cTWOM + cM + m];
#pragma unroll
    for (int i = 0; i < 4; ++i) {
      int k = j + i * 32;
      feat[k][e] = b2f(xg[(size_t)pn * cH + k]);
      feat[k + 128][e] = b2f(xg[(size_t)cn * cH + k]);
    }
    if (tid < cH) {
      float v = x_g[b * cH + tid];
#pragma unroll
      for (int e2 = 0; e2 < 8; ++e2) feat[256 + tid][e2] = v;
    }
  }
  __syncthreads();

  // ---- S hidden: 512 cols, each thread 2 cols x 8 edges, k over all 384 rows
  {
    const int j0 = tid, j1 = tid + 256;
    float acc0[8] = {0, 0, 0, 0, 0, 0, 0, 0};
    float acc1[8] = {0, 0, 0, 0, 0, 0, 0, 0};
    for (int k = 0; k < 384; ++k) {
      const float4 fa = *(const float4*)&feat[k][0];
      const float4 fb = *(const float4*)&feat[k][4];
      const float w0 = Ws1[k * 512 + j0];
      const float w1 = Ws1[k * 512 + j1];
      const float f[8] = {fa.x, fa.y, fa.z, fa.w, fb.x, fb.y, fb.z, fb.w};
#pragma unroll
      for (int e = 0; e < 8; ++e) {
        acc0[e] = fmaf(f[e], w0, acc0[e]);
        acc1[e] = fmaf(f[e], w1, acc1[e]);
      }
    }
    const float gs0 = bs1[j0];
    const float gs1 = bs1[j1];
#pragma unroll
    for (int e = 0; e < 8; ++e) {
      hid[e][j0] = fmaxf(acc0[e] + gs0, 0.f);
      hid[e][j1] = fmaxf(acc1[e] + gs1, 0.f);
    }
  }
  __syncthreads();
  // ---- S out
  {
    const int g = tid >> 3, t8 = tid & 7;
    const int e = g >> 2, o = g & 3;
    float p = 0.f;
    const int jb = t8 * 64;
    for (int i = 0; i < 64; ++i) {
      int j = jb + i;
      p = fmaf(hid[e][j], Ws2[j * 4 + o], p);
    }
    p += __shfl_down(p, 4);
    p += __shfl_down(p, 2);
    p += __shfl_down(p, 1);
    if (t8 == 0) outs_s[e][o] = p + bs2[o];
  }
  __syncthreads();
  // ---- C hidden: 384 cols
  {
    const int j0 = tid, j1 = tid + 256;
    const bool has1 = (tid < 128);
    float acc0[8] = {0, 0, 0, 0, 0, 0, 0, 0};
    float acc1[8] = {0, 0, 0, 0, 0, 0, 0, 0};
    for (int k = 0; k < 384; ++k) {
      const float4 fa = *(const float4*)&feat[k][0];
      const float4 fb = *(const float4*)&feat[k][4];
      const float w0 = Wc1[k * 384 + j0];
      const float w1 = has1 ? Wc1[k * 384 + j1] : 0.f;
      const float f[8] = {fa.x, fa.y, fa.z, fa.w, fb.x, fb.y, fb.z, fb.w};
#pragma unroll
      for (int e = 0; e < 8; ++e) {
        acc0[e] = fmaf(f[e], w0, acc0[e]);
        acc1[e] = fmaf(f[e], w1, acc1[e]);
      }
    }
    const float gc0 = bc1[j0];
    const float gc1 = has1 ? bc1[j1] : 0.f;
#pragma unroll
    for (int e = 0; e < 8; ++e) {
      hid[e][j0] = fmaxf(acc0[e] + gc0, 0.f);
      if (has1) hid[e][j1] = fmaxf(acc1[e] + gc1, 0.f);
    }
  }
  __syncthreads();
  // ---- C out
  {
    const int g = tid >> 3, t8 = tid & 7;
    if (g < 24) {
      const int e = g / 3, o = g % 3;
      float p = 0.f;
      const int jb = t8 * 48;
      for (int i = 0; i < 48; ++i) {
        int j = jb + i;
        p = fmaf(hid[e][j], Wc2[j * 3 + o], p);
      }
      p += __shfl_down(p, 4);
      p += __shfl_down(p, 2);
      p += __shfl_down(p, 1);
      if (t8 == 0) outs_c[e][o] = p + bc2[o];
    }
  }
  __syncthreads();
  if (tid < 8) {
    const int e = tid, m = m0 + e;
    const int ns = nsw[b];
    const bool mk = (m >= cM - ns);
    const float s0 = outs_s[e][0], sv1 = outs_s[e][1], sv2 = outs_s[e][2], sv3 = outs_s[e][3];
    const float c0 = outs_c[e][0], c1 = outs_c[e][1], c2 = outs_c[e][2];
    const float gt = mk ? (1.f / (1.f + expf(-s0))) : 1.f;
    const float pf = mk ? sv1 : c0;
    const float vp = mk ? sv2 : c1;
    const float vc = mk ? sv3 : c2;
    const float pfc = pf * gt;
    const int bm = b * cM + m;
    gt_w[bm] = gt; wvp_w[bm] = vp; wvc_w[bm] = vc; pfc_w[bm] = pfc;
    out[b * ZROW + m] = pfc;
    out[b * ZROW + cM + cN + m] = gt;
  }
}

// ---------------- v einsums ----------------
__global__ __launch_bounds__(256) void k_v(const float* __restrict__ incP, const float* __restrict__ incC,
                                           const float* __restrict__ wvp, const float* __restrict__ wvc,
                                           const float* __restrict__ invdeg, float* __restrict__ v_w,
                                           float* __restrict__ out) {
  const int wid = blockIdx.x * 4 + (threadIdx.x >> 6);
  const int lane = threadIdx.x & 63;
  const int b = wid / cN, n = wid % cN;
  const size_t rowoff = (size_t)(b * cN + n) * cM + lane * 8;
  const float4 p0 = *(const float4*)(incP + rowoff);
  const float4 p1 = *(const float4*)(incP + rowoff + 4);
  const float4 c0 = *(const float4*)(incC + rowoff);
  const float4 c1 = *(const float4*)(incC + rowoff + 4);
  const float* wp = wvp + b * cM + lane * 8;
  const float* wc = wvc + b * cM + lane * 8;
  float s;
  s = p0.x * wp[0] + p0.y * wp[1] + p0.z * wp[2] + p0.w * wp[3] +
      p1.x * wp[4] + p1.y * wp[5] + p1.z * wp[6] + p1.w * wp[7];
  s += c0.x * wc[0] + c0.y * wc[1] + c0.z * wc[2] + c0.w * wc[3] +
       c1.x * wc[4] + c1.y * wc[5] + c1.z * wc[6] + c1.w * wc[7];
#pragma unroll
  for (int off = 32; off >= 1; off >>= 1) s += __shfl_down(s, off);
  if (lane == 0) {
    float val = invdeg[b * cN + n] * s;
    if (n == 0) val = 1.0f;
    v_w[b * cN + n] = val;
    out[b * ZROW + cM + n] = val;
  }
}

// ---------------- q_fc = (A^T v) * graph_topo ----------------
__global__ __launch_bounds__(256) void k_qfc(const float* __restrict__ A, const float* __restrict__ v_w,
                                             const float* __restrict__ gt_w, float* __restrict__ qfc_w,
                                             float* __restrict__ out) {
  __shared__ float vs[cN];
  const int b = blockIdx.x >> 1;
  const int m = ((blockIdx.x & 1) << 8) + threadIdx.x;
  for (int i = threadIdx.x; i < cN; i += 256) vs[i] = v_w[b * cN + i];
  __syncthreads();
  float s = 0.f;
  for (int n = 0; n < cN; ++n) s = fmaf(A[n * cM + m], vs[n], s);
  const int bm = b * cM + m;
  const float q = s * gt_w[bm];
  qfc_w[bm] = q;
  out[ZBASE + b * CROW + m] = q;
}

// ---------------- pg / qg ----------------
__global__ __launch_bounds__(256) void k_pgqg(const float* __restrict__ A, const float* __restrict__ x,
                                              const float* __restrict__ pfc, const float* __restrict__ qfc,
                                              float* __restrict__ out) {
  const int idx = blockIdx.x * 256 + threadIdx.x;
  if (idx >= cNN) return;
  const int b = idx / cN, n = idx % cN;
  const float* ar = A + (size_t)n * cM;
  const float* pf = pfc + b * cM;
  const float* qf = qfc + b * cM;
  float ps = 0.f, qs = 0.f;
  for (int mm = 0; mm < cM; mm += 4) {
    const float4 ua = *(const float4*)(ar + mm);
    ps += ua.x * pf[mm] + ua.y * pf[mm + 1] + ua.z * pf[mm + 2] + ua.w * pf[mm + 3];
    qs += ua.x * qf[mm] + ua.y * qf[mm + 1] + ua.z * qf[mm + 2] + ua.w * qf[mm + 3];
  }
  out[ZBASE + b * CROW + cM + n] = x[2 * idx] + ps;
  out[ZBASE + b * CROW + cM + cN + n] = x[2 * idx + 1] + qs;
}

extern "C" void kernel_launch(void* const* d_in, const int* in_sizes, int n_in,
                              void* d_out, int out_size, void* d_ws, size_t ws_size,
                              hipStream_t stream) {
  // dict order (confirmed by r3==r4): x, edge_index, numSwitches, inv_degree,
  // inc_parents, inc_childs, A, W1, b1, W2, b2, Ws1, bs1, Ws2, bs2, Wc1, bc1, Wc2, bc2
  const bool dict_order = (in_sizes[1] == 2 * cE);  // 409600
  int IEI, INSW, IIVD, IIP, IIC, IA, IW;
  if (dict_order) { IEI = 1; INSW = 2; IIVD = 3; IIP = 4; IIC = 5; IA = 6; IW = 7; }
  else            { IIVD = 1; IIP = 2; IIC = 3; IA = 4; IW = 5; IEI = 17; INSW = 18; }

  const float* x = (const float*)d_in[0];
  const int* ei_raw = (const int*)d_in[IEI];
  const int* nsw_raw = (const int*)d_in[INSW];
  const float* invdeg = (const float*)d_in[IIVD];
  const float* incP = (const float*)d_in[IIP];
  const float* incC = (const float*)d_in[IIC];
  const float* A = (const float*)d_in[IA];
  const float* W1 = (const float*)d_in[IW + 0];
  const float* b1 = (const float*)d_in[IW + 1];
  const float* W2 = (const float*)d_in[IW + 2];
  const float* b2 = (const float*)d_in[IW + 3];
  const float* Ws1 = (const float*)d_in[IW + 4];
  const float* bs1 = (const float*)d_in[IW + 5];
  const float* Ws2 = (const float*)d_in[IW + 6];
  const float* bs2 = (const float*)d_in[IW + 7];
  const float* Wc1 = (const float*)d_in[IW + 8];
  const float* bc1 = (const float*)d_in[IW + 9];
  const float* Wc2 = (const float*)d_in[IW + 10];
  const float* bc2 = (const float*)d_in[IW + 11];
  float* out = (float*)d_out;   // reference output dtype is float32

  // ---- workspace (~83.6 MB; r2 proved >= 85.4 MB available) ----
  char* w = (char*)d_ws;
  auto alloc = [&](size_t bytes) { void* p = (void*)w; w += (bytes + 255) & ~(size_t)255; return p; };
  float* dinv = (float*)alloc((size_t)cNN * 4);
  int* ei = (int*)alloc((size_t)2 * cE * 4);
  int* nsw = (int*)alloc((size_t)cB * 4);
  bf16* hbufA = (bf16*)alloc((size_t)cNN * cH * 2);  // hraw -> h1 -> xg
  bf16* hbufB = (bf16*)alloc((size_t)cNN * cH * 2);  // h2raw
  float* agg = (float*)alloc((size_t)cNN * cH * 4);  // agg1 -> agg2
  float* x_g = (float*)alloc((size_t)cB * cH * 4);
  float* gt_w = (float*)alloc((size_t)cB * cM * 4);
  float* wvp_w = (float*)alloc((size_t)cB * cM * 4);
  float* wvc_w = (float*)alloc((size_t)cB * cM * 4);
  float* pfc_w = (float*)alloc((size_t)cB * cM * 4);
  float* qfc_w = (float*)alloc((size_t)cB * cM * 4);
  float* v_w = (float*)alloc((size_t)cB * cN * 4);

  const int NH = cNN * cH;          // 9,830,400
  k_norm_idx<<<(2 * cE) / 256, 256, 0, stream>>>(ei_raw, nsw_raw, ei, nsw);
  k_fill<<<(cNN + 255) / 256, 256, 0, stream>>>(dinv, 1.0f, cNN);   // deg init (self-loop)
  k_deg<<<cE / 256, 256, 0, stream>>>(ei, dinv);
  k_dinv<<<(cNN + 255) / 256, 256, 0, stream>>>(dinv);

  // layer 1 (literal): hraw = x@W1+b1; agg1 = scatter(hraw*norm); h1 = relu(agg1 + self)
  k_lin1<<<NH / 256, 256, 0, stream>>>(x, W1, b1, hbufA);
  k_fill<<<NH / 256, 256, 0, stream>>>(agg, 0.0f, NH);
  k_scat<<<cE * cH / 256, 256, 0, stream>>>(ei, hbufA, dinv, agg);
  k_reluagg<<<NH / 256, 256, 0, stream>>>(agg, hbufA, dinv, hbufA);  // h1 in place

  // layer 2 (literal): h2raw = h1@W2+b2; agg2 = scatter(h2raw*norm); xg = relu(agg2 + self)
  k_lin2<<<cNN / 8, 256, 0, stream>>>(hbufA, W2, b2, hbufB);
  k_fill<<<NH / 256, 256, 0, stream>>>(agg, 0.0f, NH);
  k_scat<<<cE * cH / 256, 256, 0, stream>>>(ei, hbufB, dinv, agg);
  k_reluagg<<<NH / 256, 256, 0, stream>>>(agg, hbufB, dinv, hbufA);  // xg into hbufA (h1 dead)

  bf16* xg = hbufA;
  k_xgsum<<<cB, 128, 0, stream>>>(xg, x_g);
  k_mlp<<<cB * cM / 8, 256, 0, stream>>>(ei, nsw, xg, x_g, Ws1, bs1, Ws2, bs2,
                                         Wc1, bc1, Wc2, bc2,
                                         gt_w, wvp_w, wvc_w, pfc_w, out);
  k_v<<<cB * cN / 4, 256, 0, stream>>>(incP, incC, wvp_w, wvc_w, invdeg, v_w, out);
  k_qfc<<<cB * cM / 256, 256, 0, stream>>>(A, v_w, gt_w, qfc_w, out);
  k_pgqg<<<(cNN + 255) / 256, 256, 0, stream>>>(A, x, pfc_w, qfc_w, out);
}

// Round 7
// 802.997 us; speedup vs baseline: 2.1677x; 2.1677x over previous
//
#include <hip/hip_runtime.h>
#include <hip/hip_bf16.h>

typedef __hip_bfloat16 bf16;
typedef __bf16 bf16x8 __attribute__((ext_vector_type(8)));
typedef float f32x4 __attribute__((ext_vector_type(4)));

static constexpr int cB = 200, cN = 384, cM = 512, cH = 128;
static constexpr int cNN  = cB * cN;     // 76800
static constexpr int cE   = 2 * cB * cM; // 204800 edges
static constexpr int cTWOM = 2 * cM;     // 1024
static constexpr int ZROW = 2 * cM + cN; // 1408
static constexpr int CROW = cM + 2 * cN; // 1280
static constexpr int ZBASE = cB * ZROW;  // 281600

__device__ __forceinline__ float b2f(bf16 x) { return __bfloat162float(x); }
__device__ __forceinline__ bf16  f2b(float x) { return __float2bfloat16(x); }

// ---------------- normalize edge_index / numSwitches (int32 or int64 low words) ----
__global__ __launch_bounds__(256) void k_norm_idx(const int* __restrict__ ei_raw,
                                                  const int* __restrict__ nsw_raw,
                                                  int* __restrict__ ei, int* __restrict__ nsw) {
  int z = 0;
#pragma unroll
  for (int j = 1; j < 64; j += 2) z |= ei_raw[j];
  const int f = (z == 0) ? 1 : 0;
  const int i = blockIdx.x * 256 + threadIdx.x;
  if (i < 2 * cE) ei[i] = ei_raw[i << f];
  if (blockIdx.x == 0 && threadIdx.x < cB) nsw[threadIdx.x] = nsw_raw[threadIdx.x << f];
}

__global__ __launch_bounds__(256) void k_fill(float* p, float v, int count) {
  int i = blockIdx.x * 256 + threadIdx.x;
  if (i < count) p[i] = v;
}

__global__ __launch_bounds__(256) void k_deg(const int* __restrict__ ei, float* deg) {
  int e = blockIdx.x * 256 + threadIdx.x;
  if (e < cE) atomicAdd(&deg[ei[cE + e]], 1.0f);
}

__global__ __launch_bounds__(256) void k_dinv(float* deg) {
  int i = blockIdx.x * 256 + threadIdx.x;
  if (i < cNN) deg[i] = rsqrtf(deg[i]);
}

// ---------------- layer 1 linear: hraw = x@W1 + b1 ----------------
__global__ __launch_bounds__(256) void k_lin1(const float* __restrict__ x, const float* __restrict__ W1,
                                              const float* __restrict__ b1, bf16* __restrict__ hraw) {
  int idx = blockIdx.x * 256 + threadIdx.x;
  if (idx >= cNN * cH) return;
  int n = idx >> 7, h = idx & 127;
  hraw[idx] = f2b(x[2 * n] * W1[h] + x[2 * n + 1] * W1[cH + h] + b1[h]);
}

// ---------------- edge scatter: agg[d] += h[s] * dinv[s] * dinv[d] ----------------
__global__ __launch_bounds__(256) void k_scat(const int* __restrict__ ei, const bf16* __restrict__ hsrc,
                                              const float* __restrict__ dinv, float* __restrict__ agg) {
  int idx = blockIdx.x * 256 + threadIdx.x;
  int e = idx >> 7, h = idx & 127;
  if (e >= cE) return;
  int s = ei[e], d = ei[cE + e];
  atomicAdd(&agg[(size_t)d * cH + h], b2f(hsrc[(size_t)s * cH + h]) * dinv[s] * dinv[d]);
}

// ---------------- relu(agg + self) ----------------
__global__ __launch_bounds__(256) void k_reluagg(const float* __restrict__ agg, const bf16* __restrict__ hself,
                                                 const float* __restrict__ dinv, bf16* __restrict__ outh) {
  int idx = blockIdx.x * 256 + threadIdx.x;
  if (idx >= cNN * cH) return;
  int n = idx >> 7;
  float dn = dinv[n];
  float v = agg[idx] + b2f(hself[idx]) * dn * dn;
  outh[idx] = f2b(fmaxf(v, 0.0f));
}

// ---------------- layer 2 linear: h2raw = h1@W2 + b2 ----------------
__global__ __launch_bounds__(256) void k_lin2(const bf16* __restrict__ h1, const float* __restrict__ W2,
                                              const float* __restrict__ b2v, bf16* __restrict__ h2raw) {
  __shared__ float w2s[64 * cH];
  __shared__ float ts[8][cH];
  const int tid = threadIdx.x;
  const int n0 = blockIdx.x * 8;
  for (int i = tid; i < 8 * cH; i += 256)
    ts[i >> 7][i & 127] = b2f(h1[(size_t)(n0 + (i >> 7)) * cH + (i & 127)]);
  const int hp = (tid & 63) * 2;
  const int ng = tid >> 6;
  const int e0 = ng, e1 = ng + 4;
  float a00 = 0, a01 = 0, a10 = 0, a11 = 0;
  for (int half = 0; half < 2; ++half) {
    __syncthreads();
    for (int i = tid; i < 64 * cH; i += 256) w2s[i] = W2[half * 64 * cH + i];
    __syncthreads();
    const int kb = half * 64;
#pragma unroll 8
    for (int k = 0; k < 64; ++k) {
      const float w0 = w2s[k * cH + hp];
      const float w1 = w2s[k * cH + hp + 1];
      const float t0 = ts[e0][kb + k];
      const float t1 = ts[e1][kb + k];
      a00 = fmaf(t0, w0, a00); a01 = fmaf(t0, w1, a01);
      a10 = fmaf(t1, w0, a10); a11 = fmaf(t1, w1, a11);
    }
  }
  h2raw[(size_t)(n0 + e0) * cH + hp]     = f2b(a00 + b2v[hp]);
  h2raw[(size_t)(n0 + e0) * cH + hp + 1] = f2b(a01 + b2v[hp + 1]);
  h2raw[(size_t)(n0 + e1) * cH + hp]     = f2b(a10 + b2v[hp]);
  h2raw[(size_t)(n0 + e1) * cH + hp + 1] = f2b(a11 + b2v[hp + 1]);
}

// ---------------- x_g = sum_n xg ----------------
__global__ __launch_bounds__(128) void k_xgsum(const bf16* __restrict__ xg, float* __restrict__ x_g) {
  int b = blockIdx.x, h = threadIdx.x;
  float s = 0.f;
  const bf16* p = xg + (size_t)b * cN * cH + h;
  for (int n = 0; n < cN; ++n) s += b2f(p[(size_t)n * cH]);
  x_g[b * cH + h] = s;
}

// ---------------- weight transpose+bf16: Ws1t[j][k]=Ws1[k][j], Wc1t[j][k]=Wc1[k][j] (k<256) ----
__global__ __launch_bounds__(256) void k_wt(const float* __restrict__ Ws1, const float* __restrict__ Wc1,
                                            bf16* __restrict__ Ws1t, bf16* __restrict__ Wc1t) {
  int idx = blockIdx.x * 256 + threadIdx.x;
  if (idx < 512 * 256) {
    int j = idx >> 8, k = idx & 255;
    Ws1t[idx] = f2b(Ws1[k * 512 + j]);
  }
  if (idx < 384 * 256) {
    int j = idx >> 8, k = idx & 255;
    Wc1t[idx] = f2b(Wc1[k * 384 + j]);
  }
}

// ---------------- g_s = x_g@Ws1[256:]+bs1 ; g_c = x_g@Wc1[256:]+bc1 (exact, f32) ----------
__global__ __launch_bounds__(512) void k_gsgc(const float* __restrict__ x_g, const float* __restrict__ Ws1,
                                              const float* __restrict__ bs1, const float* __restrict__ Wc1,
                                              const float* __restrict__ bc1, float* __restrict__ g_s,
                                              float* __restrict__ g_c) {
  __shared__ float xs[cH];
  const int b = blockIdx.x, tid = threadIdx.x;
  if (tid < cH) xs[tid] = x_g[b * cH + tid];
  __syncthreads();
  {
    float acc = bs1[tid];
    for (int k = 0; k < cH; ++k) acc = fmaf(xs[k], Ws1[(2 * cH + k) * 512 + tid], acc);
    g_s[b * 512 + tid] = acc;
  }
  if (tid < 384) {
    float acc = bc1[tid];
    for (int k = 0; k < cH; ++k) acc = fmaf(xs[k], Wc1[(2 * cH + k) * 384 + tid], acc);
    g_c[b * 384 + tid] = acc;
  }
}

// ---------------- per-edge MLPs via MFMA: 32 edges/block, K=256 ----------------
__global__ __launch_bounds__(256) void k_mlp_mfma(
    const int* __restrict__ ei, const int* __restrict__ nsw, const bf16* __restrict__ xg,
    const bf16* __restrict__ Ws1t, const bf16* __restrict__ Wc1t,
    const float* __restrict__ g_s, const float* __restrict__ g_c,
    const float* __restrict__ Ws2, const float* __restrict__ bs2,
    const float* __restrict__ Wc2, const float* __restrict__ bc2,
    float* __restrict__ gt_w, float* __restrict__ wvp_w, float* __restrict__ wvc_w,
    float* __restrict__ pfc_w, float* __restrict__ out) {
  constexpr int FS = 264;   // feat row stride (bf16): 2-way LDS conflicts only
  constexpr int HS = 520;   // hid row stride (bf16): conflict-free epilogue
  __shared__ __align__(16) bf16 feat[32 * FS];   // 16.5 KB
  __shared__ __align__(16) bf16 hid[32 * HS];    // 32.5 KB
  __shared__ float outs_s[32][4];
  __shared__ float outs_c[32][3];

  const int tid = threadIdx.x;
  const int b = blockIdx.x >> 4;
  const int m0 = (blockIdx.x & 15) << 5;   // 32 edges per block
  const int wv = tid >> 6, ln = tid & 63;
  const int fr = ln & 15;            // fragment row/col (lane&15)
  const int ak = (ln >> 4) * 8;      // fragment k offset

  // ---- gather feat[e][0:256] = [xg[pn] | xg[cn]] ----
  // 8 threads per edge; each thread covers 16 elements (= 2 x uint4) per half.
  {
    const int e = tid >> 3, j = tid & 7;
    const int m = m0 + e;
    const int pn = ei[b * cTWOM + m];
    const int cn = ei[b * cTWOM + cM + m];
    const uint4* ps = (const uint4*)(xg + (size_t)pn * cH);   // 16 uint4 per row
    const uint4* cs = (const uint4*)(xg + (size_t)cn * cH);
    uint4* fp = (uint4*)(feat + e * FS);          // 528-byte row stride (16-aligned)
    uint4* fc = (uint4*)(feat + e * FS + 128);
    fp[2 * j]     = ps[2 * j];
    fp[2 * j + 1] = ps[2 * j + 1];
    fc[2 * j]     = cs[2 * j];
    fc[2 * j + 1] = cs[2 * j + 1];
  }
  __syncthreads();

  // ================= S layer: hid[32][512] = relu(feat@Ws1[:256] + g_s) =============
  {
    f32x4 acc[2][8];
#pragma unroll
    for (int m = 0; m < 2; ++m)
#pragma unroll
      for (int n = 0; n < 8; ++n) acc[m][n] = f32x4{0.f, 0.f, 0.f, 0.f};
    const bf16* ap = feat + fr * FS + ak;
    const bf16* bp = Ws1t + ((size_t)(wv * 128 + fr)) * 256 + ak;
#pragma unroll
    for (int kt = 0; kt < 8; ++kt) {
      const int ko = kt * 32;
      const bf16x8 a0 = *(const bf16x8*)(ap + ko);
      const bf16x8 a1 = *(const bf16x8*)(ap + 16 * FS + ko);
#pragma unroll
      for (int nt = 0; nt < 8; ++nt) {
        const bf16x8 bf = *(const bf16x8*)(bp + nt * 16 * 256 + ko);
        acc[0][nt] = __builtin_amdgcn_mfma_f32_16x16x32_bf16(a0, bf, acc[0][nt], 0, 0, 0);
        acc[1][nt] = __builtin_amdgcn_mfma_f32_16x16x32_bf16(a1, bf, acc[1][nt], 0, 0, 0);
      }
    }
#pragma unroll
    for (int nt = 0; nt < 8; ++nt) {
      const int col = wv * 128 + nt * 16 + fr;
      const float gs = g_s[b * 512 + col];
#pragma unroll
      for (int m = 0; m < 2; ++m)
#pragma unroll
        for (int i = 0; i < 4; ++i) {
          const int row = m * 16 + (ln >> 4) * 4 + i;
          hid[row * HS + col] = f2b(fmaxf(acc[m][nt][i] + gs, 0.f));
        }
    }
  }
  __syncthreads();

  // ---- S out: smlp = hid@Ws2 + bs2 (K=512), groups of 8 threads per edge ----
  {
    const int e = tid >> 3, t8 = tid & 7;
    float p0 = 0.f, p1 = 0.f, p2 = 0.f, p3 = 0.f;
    for (int i = 0; i < 64; ++i) {
      const int j = i * 8 + t8;                 // interleaved: 2-way LDS, coalesced Ws2
      const float hv = b2f(hid[e * HS + j]);
      const float4 wv4 = *(const float4*)(Ws2 + j * 4);
      p0 = fmaf(hv, wv4.x, p0); p1 = fmaf(hv, wv4.y, p1);
      p2 = fmaf(hv, wv4.z, p2); p3 = fmaf(hv, wv4.w, p3);
    }
#pragma unroll
    for (int off = 4; off >= 1; off >>= 1) {
      p0 += __shfl_down(p0, off); p1 += __shfl_down(p1, off);
      p2 += __shfl_down(p2, off); p3 += __shfl_down(p3, off);
    }
    if (t8 == 0) {
      outs_s[e][0] = p0 + bs2[0]; outs_s[e][1] = p1 + bs2[1];
      outs_s[e][2] = p2 + bs2[2]; outs_s[e][3] = p3 + bs2[3];
    }
  }
  __syncthreads();

  // ================= C layer: hid[32][384] = relu(feat@Wc1[:256] + g_c) =============
  {
    f32x4 acc[2][6];
#pragma unroll
    for (int m = 0; m < 2; ++m)
#pragma unroll
      for (int n = 0; n < 6; ++n) acc[m][n] = f32x4{0.f, 0.f, 0.f, 0.f};
    const bf16* ap = feat + fr * FS + ak;
    const bf16* bp = Wc1t + ((size_t)(wv * 96 + fr)) * 256 + ak;
#pragma unroll
    for (int kt = 0; kt < 8; ++kt) {
      const int ko = kt * 32;
      const bf16x8 a0 = *(const bf16x8*)(ap + ko);
      const bf16x8 a1 = *(const bf16x8*)(ap + 16 * FS + ko);
#pragma unroll
      for (int nt = 0; nt < 6; ++nt) {
        const bf16x8 bf = *(const bf16x8*)(bp + nt * 16 * 256 + ko);
        acc[0][nt] = __builtin_amdgcn_mfma_f32_16x16x32_bf16(a0, bf, acc[0][nt], 0, 0, 0);
        acc[1][nt] = __builtin_amdgcn_mfma_f32_16x16x32_bf16(a1, bf, acc[1][nt], 0, 0, 0);
      }
    }
#pragma unroll
    for (int nt = 0; nt < 6; ++nt) {
      const int col = wv * 96 + nt * 16 + fr;
      const float gc = g_c[b * 384 + col];
#pragma unroll
      for (int m = 0; m < 2; ++m)
#pragma unroll
        for (int i = 0; i < 4; ++i) {
          const int row = m * 16 + (ln >> 4) * 4 + i;
          hid[row * HS + col] = f2b(fmaxf(acc[m][nt][i] + gc, 0.f));
        }
    }
  }
  __syncthreads();

  // ---- C out: cmlp = hid@Wc2 + bc2 (K=384) ----
  {
    const int e = tid >> 3, t8 = tid & 7;
    float p0 = 0.f, p1 = 0.f, p2 = 0.f;
    for (int i = 0; i < 48; ++i) {
      const int j = i * 8 + t8;
      const float hv = b2f(hid[e * HS + j]);
      p0 = fmaf(hv, Wc2[j * 3 + 0], p0);
      p1 = fmaf(hv, Wc2[j * 3 + 1], p1);
      p2 = fmaf(hv, Wc2[j * 3 + 2], p2);
    }
#pragma unroll
    for (int off = 4; off >= 1; off >>= 1) {
      p0 += __shfl_down(p0, off); p1 += __shfl_down(p1, off); p2 += __shfl_down(p2, off);
    }
    if (t8 == 0) {
      outs_c[e][0] = p0 + bc2[0]; outs_c[e][1] = p1 + bc2[1]; outs_c[e][2] = p2 + bc2[2];
    }
  }
  __syncthreads();

  // ---- combine / mask / outputs ----
  if (tid < 32) {
    const int e = tid, m = m0 + e;
    const int ns = nsw[b];
    const bool mk = (m >= cM - ns);
    const float s0 = outs_s[e][0], sv1 = outs_s[e][1], sv2 = outs_s[e][2], sv3 = outs_s[e][3];
    const float c0 = outs_c[e][0], c1 = outs_c[e][1], c2 = outs_c[e][2];
    const float gt = mk ? (1.f / (1.f + expf(-s0))) : 1.f;
    const float pf = mk ? sv1 : c0;
    const float vp = mk ? sv2 : c1;
    const float vc = mk ? sv3 : c2;
    const float pfc = pf * gt;
    const int bm = b * cM + m;
    gt_w[bm] = gt; wvp_w[bm] = vp; wvc_w[bm] = vc; pfc_w[bm] = pfc;
    out[b * ZROW + m] = pfc;
    out[b * ZROW + cM + cN + m] = gt;
  }
}

// ---------------- v einsums ----------------
__global__ __launch_bounds__(256) void k_v(const float* __restrict__ incP, const float* __restrict__ incC,
                                           const float* __restrict__ wvp, const float* __restrict__ wvc,
                                           const float* __restrict__ invdeg, float* __restrict__ v_w,
                                           float* __restrict__ out) {
  const int wid = blockIdx.x * 4 + (threadIdx.x >> 6);
  const int lane = threadIdx.x & 63;
  const int b = wid / cN, n = wid % cN;
  const size_t rowoff = (size_t)(b * cN + n) * cM + lane * 8;
  const float4 p0 = *(const float4*)(incP + rowoff);
  const float4 p1 = *(const float4*)(incP + rowoff + 4);
  const float4 c0 = *(const float4*)(incC + rowoff);
  const float4 c1 = *(const float4*)(incC + rowoff + 4);
  const float* wp = wvp + b * cM + lane * 8;
  const float* wc = wvc + b * cM + lane * 8;
  float s;
  s = p0.x * wp[0] + p0.y * wp[1] + p0.z * wp[2] + p0.w * wp[3] +
      p1.x * wp[4] + p1.y * wp[5] + p1.z * wp[6] + p1.w * wp[7];
  s += c0.x * wc[0] + c0.y * wc[1] + c0.z * wc[2] + c0.w * wc[3] +
       c1.x * wc[4] + c1.y * wc[5] + c1.z * wc[6] + c1.w * wc[7];
#pragma unroll
  for (int off = 32; off >= 1; off >>= 1) s += __shfl_down(s, off);
  if (lane == 0) {
    float val = invdeg[b * cN + n] * s;
    if (n == 0) val = 1.0f;
    v_w[b * cN + n] = val;
    out[b * ZROW + cM + n] = val;
  }
}

// ---------------- q_fc = (A^T v) * graph_topo ----------------
__global__ __launch_bounds__(256) void k_qfc(const float* __restrict__ A, const float* __restrict__ v_w,
                                             const float* __restrict__ gt_w, float* __restrict__ qfc_w,
                                             float* __restrict__ out) {
  __shared__ float vs[cN];
  const int b = blockIdx.x >> 1;
  const int m = ((blockIdx.x & 1) << 8) + threadIdx.x;
  for (int i = threadIdx.x; i < cN; i += 256) vs[i] = v_w[b * cN + i];
  __syncthreads();
  float s = 0.f;
  for (int n = 0; n < cN; ++n) s = fmaf(A[n * cM + m], vs[n], s);
  const int bm = b * cM + m;
  const float q = s * gt_w[bm];
  qfc_w[bm] = q;
  out[ZBASE + b * CROW + m] = q;
}

// ---------------- pg / qg ----------------
__global__ __launch_bounds__(256) void k_pgqg(const float* __restrict__ A, const float* __restrict__ x,
                                              const float* __restrict__ pfc, const float* __restrict__ qfc,
                                              float* __restrict__ out) {
  const int idx = blockIdx.x * 256 + threadIdx.x;
  if (idx >= cNN) return;
  const int b = idx / cN, n = idx % cN;
  const float* ar = A + (size_t)n * cM;
  const float* pf = pfc + b * cM;
  const float* qf = qfc + b * cM;
  float ps = 0.f, qs = 0.f;
  for (int mm = 0; mm < cM; mm += 4) {
    const float4 ua = *(const float4*)(ar + mm);
    ps += ua.x * pf[mm] + ua.y * pf[mm + 1] + ua.z * pf[mm + 2] + ua.w * pf[mm + 3];
    qs += ua.x * qf[mm] + ua.y * qf[mm + 1] + ua.z * qf[mm + 2] + ua.w * qf[mm + 3];
  }
  out[ZBASE + b * CROW + cM + n] = x[2 * idx] + ps;
  out[ZBASE + b * CROW + cM + cN + n] = x[2 * idx + 1] + qs;
}

extern "C" void kernel_launch(void* const* d_in, const int* in_sizes, int n_in,
                              void* d_out, int out_size, void* d_ws, size_t ws_size,
                              hipStream_t stream) {
  // dict order confirmed (r5 pass)
  const bool dict_order = (in_sizes[1] == 2 * cE);
  int IEI, INSW, IIVD, IIP, IIC, IA, IW;
  if (dict_order) { IEI = 1; INSW = 2; IIVD = 3; IIP = 4; IIC = 5; IA = 6; IW = 7; }
  else            { IIVD = 1; IIP = 2; IIC = 3; IA = 4; IW = 5; IEI = 17; INSW = 18; }

  const float* x = (const float*)d_in[0];
  const int* ei_raw = (const int*)d_in[IEI];
  const int* nsw_raw = (const int*)d_in[INSW];
  const float* invdeg = (const float*)d_in[IIVD];
  const float* incP = (const float*)d_in[IIP];
  const float* incC = (const float*)d_in[IIC];
  const float* A = (const float*)d_in[IA];
  const float* W1 = (const float*)d_in[IW + 0];
  const float* b1 = (const float*)d_in[IW + 1];
  const float* W2 = (const float*)d_in[IW + 2];
  const float* b2 = (const float*)d_in[IW + 3];
  const float* Ws1 = (const float*)d_in[IW + 4];
  const float* bs1 = (const float*)d_in[IW + 5];
  const float* Ws2 = (const float*)d_in[IW + 6];
  const float* bs2 = (const float*)d_in[IW + 7];
  const float* Wc1 = (const float*)d_in[IW + 8];
  const float* bc1 = (const float*)d_in[IW + 9];
  const float* Wc2 = (const float*)d_in[IW + 10];
  const float* bc2 = (const float*)d_in[IW + 11];
  float* out = (float*)d_out;

  // ---- workspace (same ~83.6 MB footprint as passing r5; new buffers overlay agg) ----
  char* w = (char*)d_ws;
  auto alloc = [&](size_t bytes) { void* p = (void*)w; w += (bytes + 255) & ~(size_t)255; return p; };
  float* dinv = (float*)alloc((size_t)cNN * 4);
  int* ei = (int*)alloc((size_t)2 * cE * 4);
  int* nsw = (int*)alloc((size_t)cB * 4);
  bf16* hbufA = (bf16*)alloc((size_t)cNN * cH * 2);  // hraw -> h1 -> xg
  bf16* hbufB = (bf16*)alloc((size_t)cNN * cH * 2);  // h2raw
  float* agg = (float*)alloc((size_t)cNN * cH * 4);  // dead after k_reluagg#2
  float* x_g = (float*)alloc((size_t)cB * cH * 4);
  float* gt_w = (float*)alloc((size_t)cB * cM * 4);
  float* wvp_w = (float*)alloc((size_t)cB * cM * 4);
  float* wvc_w = (float*)alloc((size_t)cB * cM * 4);
  float* pfc_w = (float*)alloc((size_t)cB * cM * 4);
  float* qfc_w = (float*)alloc((size_t)cB * cM * 4);
  float* v_w = (float*)alloc((size_t)cB * cN * 4);

  // overlays inside agg (written only after agg's last read):
  bf16* Ws1t = (bf16*)agg;                              // 512*256*2   = 262144 B
  bf16* Wc1t = (bf16*)((char*)agg + 262144);            // 384*256*2   = 196608 B
  float* g_s = (float*)((char*)agg + 458752);           // 200*512*4   = 409600 B
  float* g_c = (float*)((char*)agg + 868352);           // 200*384*4   = 307200 B

  const int NH = cNN * cH;
  k_norm_idx<<<(2 * cE) / 256, 256, 0, stream>>>(ei_raw, nsw_raw, ei, nsw);
  k_fill<<<(cNN + 255) / 256, 256, 0, stream>>>(dinv, 1.0f, cNN);
  k_deg<<<cE / 256, 256, 0, stream>>>(ei, dinv);
  k_dinv<<<(cNN + 255) / 256, 256, 0, stream>>>(dinv);

  // GCN layer 1
  k_lin1<<<NH / 256, 256, 0, stream>>>(x, W1, b1, hbufA);
  k_fill<<<NH / 256, 256, 0, stream>>>(agg, 0.0f, NH);
  k_scat<<<cE * cH / 256, 256, 0, stream>>>(ei, hbufA, dinv, agg);
  k_reluagg<<<NH / 256, 256, 0, stream>>>(agg, hbufA, dinv, hbufA);

  // GCN layer 2
  k_lin2<<<cNN / 8, 256, 0, stream>>>(hbufA, W2, b2, hbufB);
  k_fill<<<NH / 256, 256, 0, stream>>>(agg, 0.0f, NH);
  k_scat<<<cE * cH / 256, 256, 0, stream>>>(ei, hbufB, dinv, agg);
  k_reluagg<<<NH / 256, 256, 0, stream>>>(agg, hbufB, dinv, hbufA);  // xg

  bf16* xg = hbufA;
  // weight prep + per-batch g vectors (agg now dead; overlays live)
  k_wt<<<512, 256, 0, stream>>>(Ws1, Wc1, Ws1t, Wc1t);
  k_xgsum<<<cB, 128, 0, stream>>>(xg, x_g);
  k_gsgc<<<cB, 512, 0, stream>>>(x_g, Ws1, bs1, Wc1, bc1, g_s, g_c);

  // per-edge MLPs on matrix cores
  k_mlp_mfma<<<cB * 16, 256, 0, stream>>>(ei, nsw, xg, Ws1t, Wc1t, g_s, g_c,
                                          Ws2, bs2, Wc2, bc2,
                                          gt_w, wvp_w, wvc_w, pfc_w, out);

  k_v<<<cB * cN / 4, 256, 0, stream>>>(incP, incC, wvp_w, wvc_w, invdeg, v_w, out);
  k_qfc<<<cB * cM / 256, 256, 0, stream>>>(A, v_w, gt_w, qfc_w, out);
  k_pgqg<<<(cNN + 255) / 256, 256, 0, stream>>>(A, x, pfc_w, qfc_w, out);
}